// Round 3
// baseline (599.494 us; speedup 1.0000x reference)
//
#include <hip/hip_runtime.h>

// MixedLayerCond round 3: bf16 MFMA implicit-GEMM, selected branch only,
// LPT dynamic tile scheduling + finer tiles + af prefetch.
//
//  px:    x NCHW fp32 -> xt[b][cc][h][w][ci32] bf16        (33.5 MB ws)
//  pw:    w OIHW fp32 -> wt[a][cc][oc][khw][ci32] bf16      (11.0 MB ws)
//         (LDS-transpose per (a,cc,oc-pair) block; coalesced both sides)
//  sched: rank samples by descending k (ballot), emit heavy-first tile list
//         (1024 tiles = 64 samples x 2 oc-tiles x 8 row-tiles) + counter=0.
//  conv:  768 persistent blocks (3/CU) work-steal tiles. Tile = 128oc x
//         4 rows. 4 waves: wm=oc-half, wn=row-pair; wave tile 64oc x 64pos,
//         16x16x32 bf16 MFMA, acc 4x4 frags. x chunk staged per cc into LDS
//         (10 rows + halo, zero-filled); weights (af) direct from global,
//         double-buffered one khw ahead.

typedef unsigned short ushort_t;
typedef __attribute__((ext_vector_type(8))) short short8;
typedef __attribute__((ext_vector_type(4))) float f32x4;

#define CIN   256
#define COUT  256
#define HH    32
#define WW    32
#define HW    1024

// ws layout (ushort elements)
#define XT_ELEMS   16777216            // 64*8*1024*32
#define WT_OFF_0   0
#define WT_OFF_1   65536               // 8*256*1*32
#define WT_OFF_2   655360              // + 8*256*9*32
#define WT_OFF_3   2293760             // + 8*256*25*32
#define WT_ELEMS   5505024             // + 8*256*49*32
#define TILE_BYTE_OFF ((size_t)(XT_ELEMS + WT_ELEMS) * 2)   // 44,564,480
#define N_TILES    1024
#define WS_NEEDED  (TILE_BYTE_OFF + N_TILES * 2 + 64)

// LDS x tile: 10 rows x 38 cols x ci-stride 40 ushorts (16B-aligned cells,
// bf-read banks conflict-free: 20 dwords/col => 8 distinct 4-bank groups per
// 8-lane phase)
#define XS_R_STRIDE 1520               // 38*40
#define XS_C_STRIDE 40
#define XS_ELEMS    15200              // 10*1520 (30.4 KB)

__device__ inline ushort_t f2bf(float f) {
    unsigned x = __builtin_bit_cast(unsigned, f);
    unsigned r = (x + 0x7FFFu + ((x >> 16) & 1u)) >> 16;
    return (ushort_t)r;
}

// ---------------- pre-pass: x transform ----------------
__global__ __launch_bounds__(256) void px_kernel(const float* __restrict__ x,
                                                 ushort_t* __restrict__ xt) {
    const int id = blockIdx.x * 256 + threadIdx.x;   // 64*8*1024 threads
    const int hw = id & 1023;
    const int cc = (id >> 10) & 7;
    const int b  = id >> 13;
    const float* src = x + ((size_t)(b * CIN + cc * 32)) * HW + hw;
    ushort_t* dst = xt + ((size_t)((b * 8 + cc) * HW + hw)) * 32;
#pragma unroll
    for (int v = 0; v < 4; ++v) {
        short8 o;
#pragma unroll
        for (int j = 0; j < 8; ++j)
            o[j] = (short)f2bf(src[(size_t)(v * 8 + j) * HW]);
        *(short8*)(dst + v * 8) = o;
    }
}

// ---------------- pre-pass: w transform (LDS transpose) ----------------
// block = (a, cc, oc-pair): 4 * 8 * 128 = 4096 blocks.
__global__ __launch_bounds__(256) void pw_kernel(
    const float* __restrict__ w0, const float* __restrict__ w1,
    const float* __restrict__ w2, const float* __restrict__ w3,
    ushort_t* __restrict__ wt) {
    __shared__ float lds[2 * 32 * 49];               // 12.25 KB max
    const int blk = blockIdx.x;
    const int a   = blk >> 10;
    const int cc  = (blk >> 7) & 7;
    const int oc0 = (blk & 127) * 2;
    const int tid = threadIdx.x;
    const int kk  = (a == 0) ? 1 : (a == 1) ? 9 : (a == 2) ? 25 : 49;
    const float* __restrict__ w = (a == 0) ? w0 : (a == 1) ? w1 : (a == 2) ? w2 : w3;
    const size_t woff = (a == 0) ? WT_OFF_0 : (a == 1) ? WT_OFF_1
                      : (a == 2) ? WT_OFF_2 : WT_OFF_3;
    const int ckk = 32 * kk;
#pragma unroll
    for (int ocq = 0; ocq < 2; ++ocq) {              // coalesced contiguous read
        const float* src = w + ((size_t)((oc0 + ocq) * CIN + cc * 32)) * kk;
        for (int i = tid; i < ckk; i += 256) lds[ocq * ckk + i] = src[i];
    }
    __syncthreads();
    ushort_t* dst = wt + woff + ((size_t)(cc * COUT + oc0)) * kk * 32;
    const int F = 2 * kk * 32;
    for (int j = tid; j < F; j += 256) {             // coalesced contiguous write
        const int ci  = j & 31;
        const int t2  = j >> 5;
        const int khw = t2 % kk;
        const int ocq = t2 / kk;
        dst[j] = f2bf(lds[ocq * ckk + ci * kk + khw]);
    }
}

// ---------------- sched: LPT tile list + counter ----------------
// 1 block, 64 threads (one wave). Heavy branches (large k) first.
__global__ __launch_bounds__(64) void sched_kernel(const int* __restrict__ arc,
                                                   ushort_t* __restrict__ tiles,
                                                   unsigned* __restrict__ cnt) {
    const int lane = threadIdx.x;                    // == sample b
    const int ab = (int)arc[lane];
    unsigned long long m[4];
#pragma unroll
    for (int v = 0; v < 4; ++v) m[v] = __ballot(ab == v);
    int gt = 0;
#pragma unroll
    for (int v = 1; v < 4; ++v) if (v > ab) gt += __popcll(m[v]);
    const unsigned long long eq = (ab == 0) ? m[0] : (ab == 1) ? m[1]
                                : (ab == 2) ? m[2] : m[3];
    const unsigned long long lower = (lane == 0) ? 0ull : (~0ull >> (64 - lane));
    const int rank = gt + __popcll(eq & lower);
#pragma unroll
    for (int j = 0; j < 16; ++j)
        tiles[rank * 16 + j] = (ushort_t)((lane << 4) | j);
    if (lane == 0) *cnt = 0u;
}

// ---------------- main: MFMA conv body ----------------
template <int K>
__device__ void conv_body(const ushort_t* __restrict__ xt,
                          const ushort_t* __restrict__ wtb,
                          const float* __restrict__ eb,
                          int b, int cls, int oc0, int r0,
                          float* __restrict__ out, ushort_t* xs) {
    constexpr int KK  = K * K;
    constexpr int PAD = K / 2;
    const int tid  = threadIdx.x;
    const int wave = tid >> 6;
    const int lane = tid & 63;
    const int wm   = wave >> 1;        // oc half (64)
    const int wn   = wave & 1;         // row pair (2 of 4)
    const int ln   = lane & 15;
    const int q    = lane >> 4;

    f32x4 acc[4][4];
#pragma unroll
    for (int mt = 0; mt < 4; ++mt)
#pragma unroll
        for (int nt = 0; nt < 4; ++nt) acc[mt][nt] = (f32x4)0.0f;

    const size_t CCS = (size_t)COUT * KK * 32;
    const ushort_t* wcol = wtb + ((size_t)(oc0 + wm * 64 + ln)) * (KK * 32) + q * 8;
    short8 afp[4];
#pragma unroll
    for (int mt = 0; mt < 4; ++mt)
        afp[mt] = *(const short8*)&wcol[(size_t)(mt * 16 * KK) * 32];

    const ushort_t* xsrc = xt + ((size_t)b * 8) * (HW * 32);

    for (int cc = 0; cc < 8; ++cc) {
        __syncthreads();
        // stage 10 rows x 32 cols x 32 ci (invalid rows written as zeros)
#pragma unroll
        for (int i = 0; i < 5; ++i) {
            const int id = tid + i * 256;            // 1280 16B granules
            const int r  = id >> 7;
            const int gw = (id >> 2) & 31;
            const int g4 = id & 3;
            const int gr = r0 - 3 + r;
            short8 v = (short8)0;
            if (gr >= 0 && gr < HH)
                v = *(const short8*)&xsrc[((size_t)(cc * HW + gr * WW + gw)) * 32 + g4 * 8];
            *(short8*)&xs[r * XS_R_STRIDE + (gw + 3) * XS_C_STRIDE + g4 * 8] = v;
        }
        __syncthreads();

        const ushort_t* wb = wcol + (size_t)cc * CCS;
#pragma unroll 1
        for (int kh = 0; kh < K; ++kh) {
#pragma unroll
            for (int kw = 0; kw < K; ++kw) {
                const int khw = kh * K + kw;
                short8 afc[4];
#pragma unroll
                for (int mt = 0; mt < 4; ++mt) afc[mt] = afp[mt];
                {   // prefetch next khw (or next cc's khw=0)
                    int nkhw = khw + 1;
                    const ushort_t* nb = wb;
                    if (nkhw == KK) { nkhw = 0; if (cc < 7) nb = wb + CCS; }
#pragma unroll
                    for (int mt = 0; mt < 4; ++mt)
                        afp[mt] = *(const short8*)&nb[(size_t)(mt * 16 * KK + nkhw) * 32];
                }
                short8 bf[4];
#pragma unroll
                for (int nt = 0; nt < 4; ++nt) {
                    const int rl = wn * 2 + (nt >> 1) + 3 + (kh - PAD);
                    const int c  = (nt & 1) * 16 + ln + 3 + (kw - PAD);
                    bf[nt] = *(const short8*)&xs[rl * XS_R_STRIDE + c * XS_C_STRIDE + q * 8];
                }
#pragma unroll
                for (int mt = 0; mt < 4; ++mt)
#pragma unroll
                    for (int nt = 0; nt < 4; ++nt)
                        acc[mt][nt] = __builtin_amdgcn_mfma_f32_16x16x32_bf16(
                            afc[mt], bf[nt], acc[mt][nt], 0, 0, 0);
            }
        }
    }

    // epilogue: C/D layout col=lane&15 (pos), row=q*4+reg (oc)
#pragma unroll
    for (int mt = 0; mt < 4; ++mt) {
#pragma unroll
        for (int i = 0; i < 4; ++i) {
            const int oc = oc0 + wm * 64 + mt * 16 + q * 4 + i;
            const float ev = eb[(size_t)cls * COUT + oc];
            float* ob = out + ((size_t)(b * COUT + oc)) * HW;
#pragma unroll
            for (int nt = 0; nt < 4; ++nt) {
                const int row = r0 + wn * 2 + (nt >> 1);
                const int col = (nt & 1) * 16 + ln;
                ob[row * WW + col] = acc[mt][nt][i] + ev;
            }
        }
    }
}

__global__ __launch_bounds__(256, 3) void conv_mfma(
    const ushort_t* __restrict__ xt, const ushort_t* __restrict__ wt,
    const int* __restrict__ y, const int* __restrict__ arc,
    const float* __restrict__ e0, const float* __restrict__ e1,
    const float* __restrict__ e2, const float* __restrict__ e3,
    float* __restrict__ out,
    const ushort_t* __restrict__ tiles, unsigned* __restrict__ cnt) {
    __shared__ ushort_t xs[XS_ELEMS];
    __shared__ int t_sh;
    const int tid = threadIdx.x;

    // zero column halo once (cols 0-2, 35-37; never touched by staging)
    for (int i = tid; i < 240; i += 256) {
        const int g    = i & 3;
        const int cell = i >> 2;
        const int cidx = cell % 6;
        const int r    = cell / 6;
        const int col  = (cidx < 3) ? cidx : cidx + 32;
        *(short8*)&xs[r * XS_R_STRIDE + col * XS_C_STRIDE + g * 8] = (short8)0;
    }

    for (;;) {
        if (tid == 0) {
            const unsigned t = atomicAdd(cnt, 1u);
            t_sh = (t < N_TILES) ? (int)tiles[t] : -1;
        }
        __syncthreads();
        const int e = t_sh;
        __syncthreads();
        if (e < 0) break;

        const int b   = e >> 4;
        const int j   = e & 15;
        const int oc0 = (j & 1) << 7;
        const int r0  = (j >> 1) << 2;
        const int a   = __builtin_amdgcn_readfirstlane(arc[b]);
        const int cls = __builtin_amdgcn_readfirstlane(y[b]);
        switch (a) {
            case 0:  conv_body<1>(xt, wt + WT_OFF_0, e0, b, cls, oc0, r0, out, xs); break;
            case 1:  conv_body<3>(xt, wt + WT_OFF_1, e1, b, cls, oc0, r0, out, xs); break;
            case 2:  conv_body<5>(xt, wt + WT_OFF_2, e2, b, cls, oc0, r0, out, xs); break;
            default: conv_body<7>(xt, wt + WT_OFF_3, e3, b, cls, oc0, r0, out, xs); break;
        }
    }
}

// ---------------- fallback (round-1 direct conv) ----------------
__global__ __launch_bounds__(256) void cond_conv_direct(
    const float* __restrict__ x, const int* __restrict__ y,
    const int* __restrict__ arc,
    const float* __restrict__ w0, const float* __restrict__ e0,
    const float* __restrict__ w1, const float* __restrict__ e1,
    const float* __restrict__ w2, const float* __restrict__ e2,
    const float* __restrict__ w3, const float* __restrict__ e3,
    float* __restrict__ out) {
    const int b   = blockIdx.x >> 4;
    const int o0  = (blockIdx.x & 15) << 4;
    const int tid = threadIdx.x;
    const int col  = tid & 31;
    const int row0 = tid >> 5;
    int a   = __builtin_amdgcn_readfirstlane(arc[b]);
    int cls = __builtin_amdgcn_readfirstlane(y[b]);
    const int k   = (a == 0) ? 1 : (a == 1) ? 3 : (a == 2) ? 5 : 7;
    const int kk  = k * k;
    const int pad = k >> 1;
    const float* __restrict__ wp = (a == 0) ? w0 : (a == 1) ? w1 : (a == 2) ? w2 : w3;
    const float* __restrict__ ep = (a == 0) ? e0 : (a == 1) ? e1 : (a == 2) ? e2 : e3;
    __shared__ float xsh[8 * HW];
    float acc[16][4];
#pragma unroll
    for (int o = 0; o < 16; ++o)
#pragma unroll
        for (int p = 0; p < 4; ++p) acc[o][p] = 0.f;
    const float* xb = x + (size_t)b * CIN * HW;
    for (int c0 = 0; c0 < CIN; c0 += 8) {
        __syncthreads();
        const float4* src = (const float4*)(xb + c0 * HW);
        float4* dst = (float4*)xsh;
#pragma unroll
        for (int i = 0; i < 8; ++i) dst[tid + (i << 8)] = src[tid + (i << 8)];
        __syncthreads();
        for (int kh = 0; kh < k; ++kh) {
            const int dh = kh - pad;
            int raddr[4]; bool rok[4];
#pragma unroll
            for (int p = 0; p < 4; ++p) {
                const int rr = row0 + 8 * p + dh;
                rok[p] = (rr >= 0) && (rr < HH);
                raddr[p] = (rok[p] ? rr : 0) * WW;
            }
            for (int kw = 0; kw < k; ++kw) {
                const int cc2 = col + kw - pad;
                const bool cok = (cc2 >= 0) && (cc2 < WW);
                const int cofs = cok ? cc2 : 0;
                const int khw = kh * k + kw;
#pragma unroll
                for (int ci = 0; ci < 8; ++ci) {
                    float xv[4];
#pragma unroll
                    for (int p = 0; p < 4; ++p) {
                        const float v = xsh[ci * HW + raddr[p] + cofs];
                        xv[p] = (rok[p] && cok) ? v : 0.f;
                    }
                    const float* wb = wp + (size_t)o0 * CIN * kk + (size_t)(c0 + ci) * kk + khw;
#pragma unroll
                    for (int o = 0; o < 16; ++o) {
                        const float wsv = wb[(size_t)o * CIN * kk];
#pragma unroll
                        for (int p = 0; p < 4; ++p) acc[o][p] += wsv * xv[p];
                    }
                }
            }
        }
    }
    const float* erow = ep + (size_t)cls * COUT + o0;
    float* ob = out + ((size_t)b * COUT + o0) * HW;
#pragma unroll
    for (int o = 0; o < 16; ++o) {
        const float ev = erow[o];
#pragma unroll
        for (int p = 0; p < 4; ++p)
            ob[o * HW + (row0 + 8 * p) * WW + col] = acc[o][p] + ev;
    }
}

extern "C" void kernel_launch(void* const* d_in, const int* in_sizes, int n_in,
                              void* d_out, int out_size, void* d_ws, size_t ws_size,
                              hipStream_t stream) {
    const float* x   = (const float*)d_in[0];
    const int*   y   = (const int*)  d_in[1];
    const int*   arc = (const int*)  d_in[2];
    const float* w0  = (const float*)d_in[3];
    const float* e0  = (const float*)d_in[4];
    const float* w1  = (const float*)d_in[5];
    const float* e1  = (const float*)d_in[6];
    const float* w2  = (const float*)d_in[7];
    const float* e2  = (const float*)d_in[8];
    const float* w3  = (const float*)d_in[9];
    const float* e3  = (const float*)d_in[10];
    float* out = (float*)d_out;
    const int B = in_sizes[1];

    if (ws_size >= WS_NEEDED && B == 64) {
        ushort_t* xt    = (ushort_t*)d_ws;
        ushort_t* wt    = xt + XT_ELEMS;
        ushort_t* tiles = (ushort_t*)((char*)d_ws + TILE_BYTE_OFF);
        unsigned* cnt   = (unsigned*)((char*)d_ws + TILE_BYTE_OFF + N_TILES * 2);
        hipLaunchKernelGGL(px_kernel, dim3(2048), dim3(256), 0, stream, x, xt);
        hipLaunchKernelGGL(pw_kernel, dim3(4096), dim3(256), 0, stream,
                           w0, w1, w2, w3, wt);
        hipLaunchKernelGGL(sched_kernel, dim3(1), dim3(64), 0, stream,
                           arc, tiles, cnt);
        hipLaunchKernelGGL(conv_mfma, dim3(768), dim3(256), 0, stream,
                           xt, wt, y, arc, e0, e1, e2, e3, out, tiles, cnt);
    } else {
        hipLaunchKernelGGL(cond_conv_direct, dim3(B * 16), dim3(256), 0, stream,
                           x, y, arc, w0, e0, w1, e1, w2, e2, w3, e3, out);
    }
}

// Round 4
// 398.737 us; speedup vs baseline: 1.5035x; 1.5035x over previous
//
#include <hip/hip_runtime.h>

// MixedLayerCond round 4: bf16 MFMA implicit-GEMM, selected branch only.
//  - prep (ONE dispatch): pw blocks [0,4096) + px blocks [4096,6144) + sched
//    block 6144. px: x NCHW fp32 -> xt[b][cc][h][w][ci32] bf16. pw: w OIHW
//    fp32 -> wt[a][cc][oc][khw][ci32] bf16 via LDS transpose. sched: LPT
//    tile list, heavy (k>=5) samples get 16 4-row tiles, light get 8 8-row.
//  - conv: 512 persistent blocks (2/CU) work-steal tiles. Wave tile
//    64oc x (ROWS*32/2) pos, 16x16x32 bf16 MFMA, K-templated row staging
//    (ROWS+2*PAD rows, max 10 -> 30.4 KB LDS), af weights double-buffered
//    from global.

typedef unsigned short ushort_t;
typedef __attribute__((ext_vector_type(8))) short short8;
typedef __attribute__((ext_vector_type(4))) float f32x4;

#define CIN   256
#define COUT  256
#define HH    32
#define WW    32
#define HW    1024

// ws layout (ushort elements)
#define XT_ELEMS   16777216            // 64*8*1024*32
#define WT_OFF_0   0
#define WT_OFF_1   65536               // 8*256*1*32
#define WT_OFF_2   655360              // + 8*256*9*32
#define WT_OFF_3   2293760             // + 8*256*25*32
#define WT_ELEMS   5505024             // + 8*256*49*32
#define TILE_BYTE_OFF ((size_t)(XT_ELEMS + WT_ELEMS) * 2)
#define MAX_TILES  1024
#define WS_NEEDED  (TILE_BYTE_OFF + MAX_TILES * 2 + 64)

// LDS x tile: up to 10 rows x 38 cols x ci-stride 40 ushorts
#define XS_R_STRIDE 1520               // 38*40
#define XS_C_STRIDE 40
#define XS_ROWS_MAX 10
#define XS_ELEMS    15200              // 10*1520 (30.4 KB)

__device__ inline ushort_t f2bf(float f) {
    unsigned x = __builtin_bit_cast(unsigned, f);
    unsigned r = (x + 0x7FFFu + ((x >> 16) & 1u)) >> 16;
    return (ushort_t)r;
}

// ---------------- fused pre-pass: pw + px + sched ----------------
__global__ __launch_bounds__(256) void prep_kernel(
    const float* __restrict__ x,
    const float* __restrict__ w0, const float* __restrict__ w1,
    const float* __restrict__ w2, const float* __restrict__ w3,
    const int* __restrict__ arc,
    ushort_t* __restrict__ xt, ushort_t* __restrict__ wt,
    ushort_t* __restrict__ tiles, unsigned* __restrict__ cnt) {
    __shared__ float lds[2 * 32 * 49];
    const int blk = blockIdx.x;
    const int tid = threadIdx.x;

    if (blk < 4096) {                  // ---- pw: weight transform ----
        const int a   = blk >> 10;
        const int cc  = (blk >> 7) & 7;
        const int oc0 = (blk & 127) * 2;
        const int kk  = (a == 0) ? 1 : (a == 1) ? 9 : (a == 2) ? 25 : 49;
        const float* __restrict__ w = (a == 0) ? w0 : (a == 1) ? w1
                                    : (a == 2) ? w2 : w3;
        const size_t woff = (a == 0) ? WT_OFF_0 : (a == 1) ? WT_OFF_1
                          : (a == 2) ? WT_OFF_2 : WT_OFF_3;
        const int ckk = 32 * kk;
#pragma unroll
        for (int ocq = 0; ocq < 2; ++ocq) {
            const float* src = w + ((size_t)((oc0 + ocq) * CIN + cc * 32)) * kk;
            for (int i = tid; i < ckk; i += 256) lds[ocq * ckk + i] = src[i];
        }
        __syncthreads();
        ushort_t* dst = wt + woff + ((size_t)(cc * COUT + oc0)) * kk * 32;
        const int F = 2 * kk * 32;
        for (int j = tid; j < F; j += 256) {
            const int ci  = j & 31;
            const int t2  = j >> 5;
            const int khw = t2 % kk;
            const int ocq = t2 / kk;
            dst[j] = f2bf(lds[ocq * ckk + ci * kk + khw]);
        }
    } else if (blk < 6144) {           // ---- px: x transform ----
        const int id = (blk - 4096) * 256 + tid;
        const int hw = id & 1023;
        const int cc = (id >> 10) & 7;
        const int b  = id >> 13;
        const float* src = x + ((size_t)(b * CIN + cc * 32)) * HW + hw;
        ushort_t* dst = xt + ((size_t)((b * 8 + cc) * HW + hw)) * 32;
#pragma unroll
        for (int v = 0; v < 4; ++v) {
            short8 o;
#pragma unroll
            for (int j = 0; j < 8; ++j)
                o[j] = (short)f2bf(src[(size_t)(v * 8 + j) * HW]);
            *(short8*)(dst + v * 8) = o;
        }
    } else if (tid < 64) {             // ---- sched: LPT tile list ----
        const int lane = tid;          // == sample b
        const int ab = (int)arc[lane];
        unsigned long long m[4];
#pragma unroll
        for (int v = 0; v < 4; ++v) m[v] = __ballot(ab == v);
        int gt = 0;
#pragma unroll
        for (int v = 1; v < 4; ++v) if (v > ab) gt += __popcll(m[v]);
        const unsigned long long eq = (ab == 0) ? m[0] : (ab == 1) ? m[1]
                                    : (ab == 2) ? m[2] : m[3];
        const unsigned long long lower = (lane == 0) ? 0ull
                                       : (~0ull >> (64 - lane));
        const int rank = gt + __popcll(eq & lower);
        const int nh   = __popcll(m[2]) + __popcll(m[3]);   // heavy samples
        const bool heavy = (ab >= 2);
        const int myCnt = heavy ? 16 : 8;
        const int start = heavy ? 16 * rank : 16 * nh + 8 * (rank - nh);
        for (int j = 0; j < myCnt; ++j)
            tiles[start + j] = (ushort_t)((lane << 5) | j);
        if (lane == 0) { cnt[0] = 0u; cnt[1] = (unsigned)(512 + 8 * nh); }
    }
}

// ---------------- main: MFMA conv body ----------------
// ROWS output rows per tile; stages ROWS+2*PAD rows (zero-filled OOB).
template <int K, int ROWS>
__device__ void conv_body(const ushort_t* __restrict__ xt,
                          const ushort_t* __restrict__ wtb,
                          const float* __restrict__ eb,
                          int b, int cls, int oc0, int r0,
                          float* __restrict__ out, ushort_t* xs) {
    constexpr int KK    = K * K;
    constexpr int PAD   = K / 2;
    constexpr int R     = ROWS + 2 * PAD;    // staged rows (max 10)
    constexpr int NF    = ROWS;              // n-frags per wave
    constexpr int HROWS = ROWS / 2;          // rows per wn-half
    constexpr int ITER  = (R * 128) / 256;   // staging iters (exact)

    const int tid  = threadIdx.x;
    const int wave = tid >> 6;
    const int lane = tid & 63;
    const int wm   = wave >> 1;        // oc half (64)
    const int wn   = wave & 1;         // spatial half
    const int ln   = lane & 15;
    const int q    = lane >> 4;

    f32x4 acc[4][NF];
#pragma unroll
    for (int mt = 0; mt < 4; ++mt)
#pragma unroll
        for (int nt = 0; nt < NF; ++nt) acc[mt][nt] = (f32x4)0.0f;

    const size_t CCS = (size_t)COUT * KK * 32;
    const ushort_t* wcol = wtb + ((size_t)(oc0 + wm * 64 + ln)) * (KK * 32) + q * 8;
    short8 afp[4];
#pragma unroll
    for (int mt = 0; mt < 4; ++mt)
        afp[mt] = *(const short8*)&wcol[(size_t)(mt * 16 * KK) * 32];

    const ushort_t* xsrc = xt + ((size_t)b * 8) * (HW * 32);

    for (int cc = 0; cc < 8; ++cc) {
        __syncthreads();
#pragma unroll
        for (int i = 0; i < ITER; ++i) {
            const int id = tid + i * 256;
            const int r  = id >> 7;
            const int gw = (id >> 2) & 31;
            const int g4 = id & 3;
            const int gr = r0 - PAD + r;
            short8 v = (short8)0;
            if (gr >= 0 && gr < HH)
                v = *(const short8*)&xsrc[((size_t)(cc * HW + gr * WW + gw)) * 32 + g4 * 8];
            *(short8*)&xs[r * XS_R_STRIDE + (gw + 3) * XS_C_STRIDE + g4 * 8] = v;
        }
        __syncthreads();

        const ushort_t* wb = wcol + (size_t)cc * CCS;
#pragma unroll 1
        for (int kh = 0; kh < K; ++kh) {
#pragma unroll
            for (int kw = 0; kw < K; ++kw) {
                const int khw = kh * K + kw;
                short8 afc[4];
#pragma unroll
                for (int mt = 0; mt < 4; ++mt) afc[mt] = afp[mt];
                {   // prefetch next khw (or next cc's khw=0)
                    int nkhw = khw + 1;
                    const ushort_t* nb = wb;
                    if (nkhw == KK) { nkhw = 0; if (cc < 7) nb = wb + CCS; }
#pragma unroll
                    for (int mt = 0; mt < 4; ++mt)
                        afp[mt] = *(const short8*)&nb[(size_t)(mt * 16 * KK + nkhw) * 32];
                }
                short8 bf[NF];
#pragma unroll
                for (int nt = 0; nt < NF; ++nt) {
                    const int rl = wn * HROWS + (nt >> 1) + kh;
                    const int c  = (nt & 1) * 16 + ln + 3 + (kw - PAD);
                    bf[nt] = *(const short8*)&xs[rl * XS_R_STRIDE + c * XS_C_STRIDE + q * 8];
                }
#pragma unroll
                for (int mt = 0; mt < 4; ++mt)
#pragma unroll
                    for (int nt = 0; nt < NF; ++nt)
                        acc[mt][nt] = __builtin_amdgcn_mfma_f32_16x16x32_bf16(
                            afc[mt], bf[nt], acc[mt][nt], 0, 0, 0);
            }
        }
    }

    // epilogue: C/D layout col=lane&15 (pos), row=q*4+reg (oc)
#pragma unroll
    for (int mt = 0; mt < 4; ++mt) {
#pragma unroll
        for (int i = 0; i < 4; ++i) {
            const int oc = oc0 + wm * 64 + mt * 16 + q * 4 + i;
            const float ev = eb[(size_t)cls * COUT + oc];
            float* ob = out + ((size_t)(b * COUT + oc)) * HW;
#pragma unroll
            for (int nt = 0; nt < NF; ++nt) {
                const int row = r0 + wn * HROWS + (nt >> 1);
                const int col = (nt & 1) * 16 + ln;
                ob[row * WW + col] = acc[mt][nt][i] + ev;
            }
        }
    }
}

__global__ __launch_bounds__(256, 2) void conv_mfma(
    const ushort_t* __restrict__ xt, const ushort_t* __restrict__ wt,
    const int* __restrict__ y, const int* __restrict__ arc,
    const float* __restrict__ e0, const float* __restrict__ e1,
    const float* __restrict__ e2, const float* __restrict__ e3,
    float* __restrict__ out,
    const ushort_t* __restrict__ tiles, unsigned* __restrict__ cnt) {
    __shared__ ushort_t xs[XS_ELEMS];
    __shared__ int t_sh;
    const int tid = threadIdx.x;
    const unsigned T = cnt[1];

    // zero column halo once (cols 0-2, 35-37; staging never writes them)
    for (int i = tid; i < 240; i += 256) {
        const int g    = i & 3;
        const int cell = i >> 2;
        const int cidx = cell % 6;
        const int r    = cell / 6;
        const int col  = (cidx < 3) ? cidx : cidx + 32;
        *(short8*)&xs[r * XS_R_STRIDE + col * XS_C_STRIDE + g * 8] = (short8)0;
    }

    for (;;) {
        if (tid == 0) {
            const unsigned t = atomicAdd(cnt, 1u);
            t_sh = (t < T) ? (int)tiles[t] : -1;
        }
        __syncthreads();
        const int e = t_sh;
        __syncthreads();
        if (e < 0) break;

        const int b   = e >> 5;
        const int j   = e & 31;
        const int oc0 = (j & 1) << 7;
        const int a   = __builtin_amdgcn_readfirstlane(arc[b]);
        const int cls = __builtin_amdgcn_readfirstlane(y[b]);
        switch (a) {
            case 0:  conv_body<1, 8>(xt, wt + WT_OFF_0, e0, b, cls, oc0,
                                     (j >> 1) << 3, out, xs); break;
            case 1:  conv_body<3, 8>(xt, wt + WT_OFF_1, e1, b, cls, oc0,
                                     (j >> 1) << 3, out, xs); break;
            case 2:  conv_body<5, 4>(xt, wt + WT_OFF_2, e2, b, cls, oc0,
                                     (j >> 1) << 2, out, xs); break;
            default: conv_body<7, 4>(xt, wt + WT_OFF_3, e3, b, cls, oc0,
                                     (j >> 1) << 2, out, xs); break;
        }
    }
}

// ---------------- fallback (round-1 direct conv) ----------------
__global__ __launch_bounds__(256) void cond_conv_direct(
    const float* __restrict__ x, const int* __restrict__ y,
    const int* __restrict__ arc,
    const float* __restrict__ w0, const float* __restrict__ e0,
    const float* __restrict__ w1, const float* __restrict__ e1,
    const float* __restrict__ w2, const float* __restrict__ e2,
    const float* __restrict__ w3, const float* __restrict__ e3,
    float* __restrict__ out) {
    const int b   = blockIdx.x >> 4;
    const int o0  = (blockIdx.x & 15) << 4;
    const int tid = threadIdx.x;
    const int col  = tid & 31;
    const int row0 = tid >> 5;
    int a   = __builtin_amdgcn_readfirstlane(arc[b]);
    int cls = __builtin_amdgcn_readfirstlane(y[b]);
    const int k   = (a == 0) ? 1 : (a == 1) ? 3 : (a == 2) ? 5 : 7;
    const int kk  = k * k;
    const int pad = k >> 1;
    const float* __restrict__ wp = (a == 0) ? w0 : (a == 1) ? w1 : (a == 2) ? w2 : w3;
    const float* __restrict__ ep = (a == 0) ? e0 : (a == 1) ? e1 : (a == 2) ? e2 : e3;
    __shared__ float xsh[8 * HW];
    float acc[16][4];
#pragma unroll
    for (int o = 0; o < 16; ++o)
#pragma unroll
        for (int p = 0; p < 4; ++p) acc[o][p] = 0.f;
    const float* xb = x + (size_t)b * CIN * HW;
    for (int c0 = 0; c0 < CIN; c0 += 8) {
        __syncthreads();
        const float4* src = (const float4*)(xb + c0 * HW);
        float4* dst = (float4*)xsh;
#pragma unroll
        for (int i = 0; i < 8; ++i) dst[tid + (i << 8)] = src[tid + (i << 8)];
        __syncthreads();
        for (int kh = 0; kh < k; ++kh) {
            const int dh = kh - pad;
            int raddr[4]; bool rok[4];
#pragma unroll
            for (int p = 0; p < 4; ++p) {
                const int rr = row0 + 8 * p + dh;
                rok[p] = (rr >= 0) && (rr < HH);
                raddr[p] = (rok[p] ? rr : 0) * WW;
            }
            for (int kw = 0; kw < k; ++kw) {
                const int cc2 = col + kw - pad;
                const bool cok = (cc2 >= 0) && (cc2 < WW);
                const int cofs = cok ? cc2 : 0;
                const int khw = kh * k + kw;
#pragma unroll
                for (int ci = 0; ci < 8; ++ci) {
                    float xv[4];
#pragma unroll
                    for (int p = 0; p < 4; ++p) {
                        const float v = xsh[ci * HW + raddr[p] + cofs];
                        xv[p] = (rok[p] && cok) ? v : 0.f;
                    }
                    const float* wb = wp + (size_t)o0 * CIN * kk + (size_t)(c0 + ci) * kk + khw;
#pragma unroll
                    for (int o = 0; o < 16; ++o) {
                        const float wsv = wb[(size_t)o * CIN * kk];
#pragma unroll
                        for (int p = 0; p < 4; ++p) acc[o][p] += wsv * xv[p];
                    }
                }
            }
        }
    }
    const float* erow = ep + (size_t)cls * COUT + o0;
    float* ob = out + (size_t)(b * COUT + o0) * HW;
#pragma unroll
    for (int o = 0; o < 16; ++o) {
        const float ev = erow[o];
#pragma unroll
        for (int p = 0; p < 4; ++p)
            ob[o * HW + (row0 + 8 * p) * WW + col] = acc[o][p] + ev;
    }
}

extern "C" void kernel_launch(void* const* d_in, const int* in_sizes, int n_in,
                              void* d_out, int out_size, void* d_ws, size_t ws_size,
                              hipStream_t stream) {
    const float* x   = (const float*)d_in[0];
    const int*   y   = (const int*)  d_in[1];
    const int*   arc = (const int*)  d_in[2];
    const float* w0  = (const float*)d_in[3];
    const float* e0  = (const float*)d_in[4];
    const float* w1  = (const float*)d_in[5];
    const float* e1  = (const float*)d_in[6];
    const float* w2  = (const float*)d_in[7];
    const float* e2  = (const float*)d_in[8];
    const float* w3  = (const float*)d_in[9];
    const float* e3  = (const float*)d_in[10];
    float* out = (float*)d_out;
    const int B = in_sizes[1];

    if (ws_size >= WS_NEEDED && B == 64) {
        ushort_t* xt    = (ushort_t*)d_ws;
        ushort_t* wt    = xt + XT_ELEMS;
        ushort_t* tiles = (ushort_t*)((char*)d_ws + TILE_BYTE_OFF);
        unsigned* cnt   = (unsigned*)((char*)d_ws + TILE_BYTE_OFF + MAX_TILES * 2);
        hipLaunchKernelGGL(prep_kernel, dim3(6145), dim3(256), 0, stream,
                           x, w0, w1, w2, w3, arc, xt, wt, tiles, cnt);
        hipLaunchKernelGGL(conv_mfma, dim3(512), dim3(256), 0, stream,
                           xt, wt, y, arc, e0, e1, e2, e3, out, tiles, cnt);
    } else {
        hipLaunchKernelGGL(cond_conv_direct, dim3(B * 16), dim3(256), 0, stream,
                           x, y, arc, w0, e0, w1, e1, w2, e2, w3, e3, out);
    }
}